// Round 12
// baseline (1201.789 us; speedup 1.0000x reference)
//
#include <hip/hip_runtime.h>

#define B_  64
#define T_  168
#define M_  256
#define F_  32
#define H_  128
#define O_  32
#define BT_ (B_*T_)   // 10752

typedef __attribute__((ext_vector_type(8))) short bh8;   // 8 x bf16 bits (4 VGPR)
typedef __attribute__((ext_vector_type(4))) short sh4;   // 4 x bf16 bits (8B)
typedef __attribute__((ext_vector_type(4))) float fx4;

static __device__ __forceinline__ short f2bf(float f) {
  unsigned u = __float_as_uint(f);
  u += 0x7FFFu + ((u >> 16) & 1u);   // round-to-nearest-even
  return (short)(u >> 16);
}
static __device__ __forceinline__ unsigned cvtpk(float lo, float hi) {
  unsigned r;
  asm("v_cvt_pk_bf16_f32 %0, %1, %2" : "=v"(r) : "v"(lo), "v"(hi));
  return r;
}
static __device__ __forceinline__ float ex2_(float x) {
#if __has_builtin(__builtin_amdgcn_exp2f)
  return __builtin_amdgcn_exp2f(x);
#else
  return exp2f(x);
#endif
}
static __device__ __forceinline__ float rcp_(float x) {
#if __has_builtin(__builtin_amdgcn_rcpf)
  return __builtin_amdgcn_rcpf(x);
#else
  return 1.0f / x;
#endif
}
static __device__ __forceinline__ float sigm(float x) {
  return 1.0f / (1.0f + __expf(-x));
}
static __device__ __forceinline__ float tanh_f(float x) {
  return 1.0f - 2.0f / (1.0f + __expf(2.0f * x));
}
static __device__ __forceinline__ fx4 mm16(bh8 a, bh8 b, fx4 c) {
  return __builtin_amdgcn_mfma_f32_16x16x32_bf16(a, b, c, 0, 0, 0);
}
static __device__ __forceinline__ bh8 cvt8(fx4 p0, fx4 p1) {
  bh8 s;
  s[0] = f2bf(p0[0]); s[1] = f2bf(p0[1]); s[2] = f2bf(p0[2]); s[3] = f2bf(p0[3]);
  s[4] = f2bf(p1[0]); s[5] = f2bf(p1[1]); s[6] = f2bf(p1[2]); s[7] = f2bf(p1[3]);
  return s;
}

// ================== NEW PATH (needs 352MB workspace) ==================

// ---- K1: x [bt][n][a] f32 -> u [a][bt][n] bf16, atan applied once.
__global__ __launch_bounds__(512) void atan_tr(const float* __restrict__ x,
                                               short* __restrict__ ut) {
  __shared__ __align__(16) short tl[8 * 32 * 68];   // 34.8KB -> 4 blocks/CU
  const int tid = threadIdx.x;
  const float c2p = 0.63661977236758134f;  // 2/pi
  for (int it = 0; it < 21; ++it) {
    const int id = blockIdx.x + it * 256;       // 5376 tiles total
    const int bt0 = (id >> 2) * 8, n0 = (id & 3) * 64;
    if (it) __syncthreads();
#pragma unroll
    for (int i = 0; i < 8; ++i) {
      int idx = tid + i * 512;
      int aq = idx & 7, nl = (idx >> 3) & 63, btl = idx >> 9;
      const float* src = x + (long)(bt0 + btl) * 8192 + (n0 + nl) * 32 + aq * 4;
      fx4 v = *(const fx4*)src;
      int base = (btl * 32 + aq * 4) * 68 + nl;
#pragma unroll
      for (int k = 0; k < 4; ++k)
        tl[base + k * 68] = f2bf(atanf(v[k]) * c2p);
    }
    __syncthreads();
#pragma unroll
    for (int p = 0; p < 8; ++p) {
      int r = p * 32 + (tid >> 4);              // (a, btl) row
      int a = r >> 3, btl = r & 7, nq = tid & 15;
      sh4 v = *(const sh4*)&tl[(btl * 32 + a) * 68 + nq * 4];
      *(sh4*)&ut[((long)a * BT_ + bt0 + btl) * 256 + n0 + nq * 4] = v;
    }
  }
}

// ---- K2 v2: y[a][bt][m] (bf16) = W[a] (m x n) * u[a] (n x bt).
// BOTH W-halves' A-frags hoisted to registers -> u streamed once.
__global__ __launch_bounds__(512) void icfa_gemm2(const short* __restrict__ ut,
                                                  const float* __restrict__ aw,
                                                  short* __restrict__ y) {
  __shared__ __align__(16) short waf[8 * 8 * 64 * 8];   // 64KB A-frag staging
  __shared__ __align__(16) short ubf[64 * 256];         // 32KB swizzled B tile
  const int tid = threadIdx.x;
  const int lane = tid & 63, w = tid >> 6, l15 = lane & 15, l4 = lane >> 4;
  const int a = blockIdx.x >> 3, s = blockIdx.x & 7;
  const long ua = (long)a * BT_;

  bh8 Af[2][8];
#pragma unroll
  for (int mh = 0; mh < 2; ++mh) {
    if (mh) __syncthreads();              // Af[0] hoist reads done before repack
    for (int i = 0; i < 8; ++i) {
      int idx = tid + i * 512;
      int ln = idx & 63, ks = (idx >> 6) & 7, mt = idx >> 9;
      const float* src = aw + a * 65536 + (mh * 128 + mt * 16 + (ln & 15)) * 256
                         + ks * 32 + (ln >> 4) * 8;
      *(bh8*)&waf[idx * 8] = cvt8(*(const fx4*)src, *(const fx4*)(src + 4));
    }
    __syncthreads();
#pragma unroll
    for (int ks = 0; ks < 8; ++ks)
      Af[mh][ks] = *(const bh8*)&waf[((w * 8 + ks) * 64 + lane) * 8];
  }

  for (int tile = 0; tile < 21; ++tile) {
    const int bt0 = s * 1344 + tile * 64;
    __syncthreads();   // prev tile's ubf reads done
#pragma unroll
    for (int i = 0; i < 4; ++i) {
      int idx = tid + i * 512;               // 16B units
      int row = idx >> 5, slot = idx & 31;
      bh8 v = *(const bh8*)&ut[(ua + bt0 + row) * 256 + slot * 8];
      int sb = (row * 512 + slot * 16) ^ ((row & 7) << 4);
      *(bh8*)&((char*)ubf)[sb] = v;
    }
    __syncthreads();
#pragma unroll
    for (int ct = 0; ct < 4; ++ct) {
      fx4 acc0 = {0.f, 0.f, 0.f, 0.f};
      fx4 acc1 = {0.f, 0.f, 0.f, 0.f};
      const int btr = ct * 16 + l15;
#pragma unroll
      for (int ks = 0; ks < 8; ++ks) {
        int byo = (btr * 512 + ks * 64 + l4 * 16) ^ ((btr & 7) << 4);
        bh8 Bf = *(const bh8*)&((char*)ubf)[byo];
        acc0 = mm16(Af[0][ks], Bf, acc0);
        acc1 = mm16(Af[1][ks], Bf, acc1);
      }
      sh4 o0, o1;
      o0[0] = f2bf(acc0[0]); o0[1] = f2bf(acc0[1]);
      o0[2] = f2bf(acc0[2]); o0[3] = f2bf(acc0[3]);
      o1[0] = f2bf(acc1[0]); o1[1] = f2bf(acc1[1]);
      o1[2] = f2bf(acc1[2]); o1[3] = f2bf(acc1[3]);
      long yb = (ua + bt0 + btr) * 256 + w * 16 + l4 * 4;
      *(sh4*)&y[yb]       = o0;
      *(sh4*)&y[yb + 128] = o1;
    }
  }
}

// ---- Stage 2 v12: v11 with ONE isolated change: Whh gates 0-1 held in
// VGPR (wrg[2][4], +32 VGPR, still <=128 so 16-wave occupancy keeps), whf
// shrinks to gates 2-3 (64KB). whf LDS traffic per t halves (256->128KB).
__global__ __launch_bounds__(1024) void lstm_fused12(
    const short* __restrict__ y,
    const float* __restrict__ Wih, const float* __restrict__ Whh,
    const float* __restrict__ bih, const float* __restrict__ bhh,
    const float* __restrict__ dW,  const float* __restrict__ db,
    float* __restrict__ out) {
  __shared__ __align__(16) short whf[32768];  // 64KB Whh A-frags gates 2-3
  __shared__ __align__(16) short hx[8704];    // 17.4KB h [64][128+8] stride 272B
  __shared__ __align__(16) short ytr[2048];   // 4KB y frags (swizzled half layout)
  const int tid = threadIdx.x;
  const int lane = tid & 63, w = tid >> 6, l15 = lane & 15, l4 = lane >> 4;
  const int wg = w & 7, hw = w >> 3;
  const int bidx = blockIdx.x >> 2, m0 = (blockIdx.x & 3) * 64;
  const float L2E = 1.4426950408889634f;

  // ---- pack whf gates 2-3 wave-contiguous: idx = (wg*8 + (g-2)*4 + ks)*64 + ln
  for (int i = 0; i < 4; ++i) {
    int idx = tid + i * 1024;                   // 0..4095
    int ln = idx & 63, ks = (idx >> 6) & 3, gm2 = (idx >> 8) & 1, wgp = idx >> 9;
    const float* src = Whh + (((gm2 + 2) * 8 + wgp) * 16 + (ln & 15)) * 128
                       + ks * 32 + (ln >> 4) * 8;
    *(bh8*)&whf[idx * 8] = cvt8(*(const fx4*)src, *(const fx4*)(src + 4));
  }
  // ---- h0 = 0 (8704 shorts = 4352 ints)
  for (int i = 0; i < 5; ++i) {
    int j = tid + i * 1024;
    if (j < 4352) ((int*)hx)[j] = 0;
  }
  // ---- Whh gates 0-1 A-frags in registers
  bh8 wrg[2][4];
#pragma unroll
  for (int g = 0; g < 2; ++g)
#pragma unroll
    for (int ks = 0; ks < 4; ++ks) {
      const float* src = Whh + ((g * 8 + wg) * 16 + l15) * 128 + ks * 32 + l4 * 8;
      wrg[g][ks] = cvt8(*(const fx4*)src, *(const fx4*)(src + 4));
    }

  // ---- Wih A-frags + per-row folded biases (D row g = grow + l4*4 + r)
  bh8 wfih[4]; float nb[4][4];
#pragma unroll
  for (int gate = 0; gate < 4; ++gate) {
    int grow = (gate * 8 + wg) * 16;
    const float* src = Wih + (grow + l15) * 32 + l4 * 8;
    wfih[gate] = cvt8(*(const fx4*)src, *(const fx4*)(src + 4));
#pragma unroll
    for (int r = 0; r < 4; ++r) {
      int g = grow + l4 * 4 + r;
      float b = bih[g] + bhh[g];
      nb[gate][r] = (gate == 2) ? (2.0f * L2E * b) : (-L2E * b);
    }
  }
  // ---- dense A-frags: waves wg<4: oc = wg&1, m-tile mt_d = 2hw + (wg>>1)
  bh8 df[4]; float dbv[4];
  const int oc = wg & 1, mt_d = hw * 2 + ((wg >> 1) & 1);
#pragma unroll
  for (int ks = 0; ks < 4; ++ks) {
    const float* src = dW + (oc * 16 + l15) * 128 + ks * 32 + l4 * 8;
    df[ks] = cvt8(*(const fx4*)src, *(const fx4*)(src + 4));
  }
#pragma unroll
  for (int r = 0; r < 4; ++r) dbv[r] = db[oc * 16 + l4 * 4 + r];

  float cst[2][4];
#pragma unroll
  for (int mt = 0; mt < 2; ++mt)
#pragma unroll
    for (int r = 0; r < 4; ++r) cst[mt][r] = 0.f;

  // ---- address bases (hx stride 272B; all loop offsets immediates)
  char* hxc = (char*)hx;
  const int hrb = (hw * 32 + l15) * 272 + l4 * 16;        // gates B read, tile 2hw
  const int hdb = (mt_d * 16 + l15) * 272 + l4 * 16;      // dense B read
  const int hwb = (hw * 32 + l15) * 272 + wg * 32 + l4 * 8;  // h b64 write
  // y-read mapping: thread -> (attr ar, m-pair mq2)
  const int ar = tid >> 5, mq2 = tid & 31;
  const long yrow = (long)ar * BT_ + (long)bidx * T_;
  // ytr WRITE indices (swizzled half layout); R0 even
  const int ml0 = mq2 * 2;
  const int R0 = (ml0 >> 4) * 64 + ((ar >> 3) << 4) + (ml0 & 15);
  const int eA = ar & 7, hA = eA >> 2, ehA = eA & 3;
  const int rl0 = (R0 & 15) ^ ((R0 >> 6) & 3);
  const int yw0 = hA * 1024 + rl0 * 4 + ((R0 >> 4) & 15) * 64 + ehA;
  const int yw1 = yw0 + 4 - 8 * (rl0 & 1);     // row R0+1 (flip bit0 of rl)
  // ytr READ bases (per wave: tiles 2hw, 2hw+1), b64 each half
  const int mtA = 2 * hw, mtB = 2 * hw + 1;
  const int ybA0 = ((lane & 15) ^ (mtA & 3)) * 4 + (mtA * 4 + l4) * 64;        // h=0
  const int ybB0 = ((lane & 15) ^ (mtB & 3)) * 4 + (mtB * 4 + l4) * 64;        // h=0
  // dense out base
  const long obB = (long)bidx * T_ * 8192
                 + (long)(m0 + mt_d * 16 + l15) * 32 + oc * 16 + l4 * 4;

  // ---- prologue: ytr(0), prefetch y(1)
  int ys = *(const int*)&y[(yrow + 0) * 256 + m0 + mq2 * 2];
  ytr[yw0] = (short)(ys & 0xffff);
  ytr[yw1] = (short)(((unsigned)ys) >> 16);
  ys = *(const int*)&y[(yrow + 1) * 256 + m0 + mq2 * 2];
  __syncthreads();

  for (int t = 0; t < T_; ++t) {
    // ---- phase A: gates GEMM D[g][m] + dense(t-1) + pointwise
    int ysn = 0;
    if (t + 2 < T_) ysn = *(const int*)&y[(yrow + t + 2) * 256 + m0 + mq2 * 2];
    fx4 acc[4][2];
    {
      sh4 a0 = *(const sh4*)&ytr[ybA0];
      sh4 a1 = *(const sh4*)&ytr[ybA0 + 1024];
      sh4 b0 = *(const sh4*)&ytr[ybB0];
      sh4 b1 = *(const sh4*)&ytr[ybB0 + 1024];
      bh8 yB0 = __builtin_shufflevector(a0, a1, 0, 1, 2, 3, 4, 5, 6, 7);
      bh8 yB1 = __builtin_shufflevector(b0, b1, 0, 1, 2, 3, 4, 5, 6, 7);
      fx4 Z = {0.f, 0.f, 0.f, 0.f};
#pragma unroll
      for (int g = 0; g < 4; ++g) {
        acc[g][0] = mm16(wfih[g], yB0, Z);
        acc[g][1] = mm16(wfih[g], yB1, Z);
      }
    }
#pragma unroll
    for (int ks = 0; ks < 4; ++ks) {
      bh8 hB0 = *(const bh8*)(hxc + hrb + ks * 64);
      bh8 hB1 = *(const bh8*)(hxc + hrb + 4352 + ks * 64);
#pragma unroll
      for (int g = 0; g < 2; ++g) {
        acc[g][0] = mm16(wrg[g][ks], hB0, acc[g][0]);
        acc[g][1] = mm16(wrg[g][ks], hB1, acc[g][1]);
      }
#pragma unroll
      for (int g = 2; g < 4; ++g) {
        bh8 Af = *(const bh8*)((const char*)whf
                               + ((wg * 8 + (g - 2) * 4 + ks) * 64 + lane) * 16);
        acc[g][0] = mm16(Af, hB0, acc[g][0]);
        acc[g][1] = mm16(Af, hB1, acc[g][1]);
      }
    }
    // dense head for t-1 (reads hx = h_{t-1}) -> contiguous fx4 global store
    if (wg < 4 && t > 0) {
      fx4 A = {dbv[0], dbv[1], dbv[2], dbv[3]};
#pragma unroll
      for (int ks = 0; ks < 4; ++ks) {
        bh8 hd = *(const bh8*)(hxc + hdb + ks * 64);
        A = mm16(df[ks], hd, A);
      }
      *(fx4*)&out[obB + (long)(t - 1) * 8192] = A;
    }
    // pointwise: rcp-merged, 5 exp2 + 2 rcp per cell
    float hn[2][4];
#pragma unroll
    for (int mt = 0; mt < 2; ++mt)
#pragma unroll
      for (int r = 0; r < 4; ++r) {
        float eI = ex2_(fmaf(acc[0][mt][r], -L2E, nb[0][r]));      // e^{-i'}
        float eF = ex2_(fmaf(acc[1][mt][r], -L2E, nb[1][r]));      // e^{-f'}
        float eG = ex2_(fmaf(acc[2][mt][r], 2.f * L2E, nb[2][r])); // e^{2g'}
        float eO = ex2_(fmaf(acc[3][mt][r], -L2E, nb[3][r]));      // e^{-o'}
        float pi = 1.f + eI, pf = 1.f + eF, pg = 1.f + eG;
        float pig = pi * pg;
        float num = fmaf(cst[mt][r], pig, (eG - 1.f) * pf);
        float cn = num * rcp_(pf * pig);
        cst[mt][r] = cn;
        float eC = ex2_(cn * (2.f * L2E));                         // e^{2cn}
        hn[mt][r] = (eC - 1.f) * rcp_((1.f + eO) * (1.f + eC));
      }
    __syncthreads();                       // B_A: all hx/ytr reads done
    // ---- phase B: write hx <- h_t (one b64 per m-tile), ytr <- y(t+1)
#pragma unroll
    for (int mt = 0; mt < 2; ++mt) {
      unsigned p01 = cvtpk(hn[mt][0], hn[mt][1]);
      unsigned p23 = cvtpk(hn[mt][2], hn[mt][3]);
      *(unsigned long long*)(hxc + hwb + mt * 4352) =
          (((unsigned long long)p23) << 32) | p01;
    }
    if (t + 1 < T_) {
      ytr[yw0] = (short)(ys & 0xffff);
      ytr[yw1] = (short)(((unsigned)ys) >> 16);
    }
    ys = ysn;
    __syncthreads();                       // B_B: writes visible
  }
  // ---- epilogue: dense(T-1) from hx = h_{T-1}
  if (wg < 4) {
    fx4 A = {dbv[0], dbv[1], dbv[2], dbv[3]};
#pragma unroll
    for (int ks = 0; ks < 4; ++ks) {
      bh8 hd = *(const bh8*)(hxc + hdb + ks * 64);
      A = mm16(df[ks], hd, A);
    }
    *(fx4*)&out[obB + (long)(T_ - 1) * 8192] = A;
  }
}

// ================== OLD PATH (fallback if workspace too small) ==================

__global__ __launch_bounds__(512) void icfa_mfma(const float* __restrict__ x,
                                                 const float* __restrict__ aw,
                                                 float* __restrict__ y) {
  __shared__ short waf[8 * 8 * 64 * 8];
  __shared__ short ubf[64 * 264];
  const int tid = threadIdx.x;
  const int lane = tid & 63, w = tid >> 6, l15 = lane & 15, l4 = lane >> 4;
  const int a = blockIdx.x >> 3, s = blockIdx.x & 7;
  const float c2p = 0.63661977236758134f;

  for (int mh = 0; mh < 2; ++mh) {
    __syncthreads();
    for (int i = 0; i < 8; ++i) {
      int idx = tid + i * 512;
      int ln = idx & 63, ks = (idx >> 6) & 7, mt = idx >> 9;
      const float* src = aw + a * 65536 + (mh * 128 + mt * 16 + (ln & 15)) * 256
                         + ks * 32 + (ln >> 4) * 8;
      *(bh8*)&waf[idx * 8] = cvt8(*(const fx4*)src, *(const fx4*)(src + 4));
    }
    __syncthreads();
    bh8 Af[8];
#pragma unroll
    for (int ks = 0; ks < 8; ++ks)
      Af[ks] = *(const bh8*)&waf[((w * 8 + ks) * 64 + lane) * 8];

    for (int tile = 0; tile < 21; ++tile) {
      const int bt0 = s * 1344 + tile * 64;
      __syncthreads();
#pragma unroll 4
      for (int i = 0; i < 32; ++i) {
        int idx = tid + i * 512;
        int n = idx & 255, btc = idx >> 8;
        float v = x[(long)(bt0 + btc) * 8192 + n * 32 + a];
        ubf[btc * 264 + n] = f2bf(atanf(v) * c2p);
      }
      __syncthreads();
#pragma unroll
      for (int ct = 0; ct < 4; ++ct) {
        fx4 acc = {0.f, 0.f, 0.f, 0.f};
#pragma unroll
        for (int ks = 0; ks < 8; ++ks) {
          bh8 Bf = *(const bh8*)&ubf[(ct * 16 + l15) * 264 + ks * 32 + l4 * 8];
          acc = mm16(Af[ks], Bf, acc);
        }
        long ybase = (long)(bt0 + ct * 16 + l15) * 8192
                     + (mh * 128 + w * 16 + l4 * 4) * 32 + a;
#pragma unroll
        for (int r = 0; r < 4; ++r) y[ybase + (long)r * 32] = acc[r];
      }
    }
  }
}

__global__ __launch_bounds__(512) void lstm_fused(
    const float* __restrict__ Wih, const float* __restrict__ Whh,
    const float* __restrict__ bih, const float* __restrict__ bhh,
    const float* __restrict__ dW,  const float* __restrict__ db,
    float* __restrict__ yo) {
  __shared__ short whf[32 * 4 * 64 * 8];
  __shared__ short hbuf[4 * 4 * 64 * 8];
  __shared__ short ytr[4 * 64 * 8];
  __shared__ float obuf[64 * 36];
  const int tid = threadIdx.x;
  const int lane = tid & 63, w = tid >> 6, l15 = lane & 15, l4 = lane >> 4;
  const int bidx = blockIdx.x >> 2, m0 = (blockIdx.x & 3) * 64;

  for (int i = 0; i < 16; ++i) {
    int idx = tid + i * 512;
    int ln = idx & 63, ks = (idx >> 6) & 3, ct = idx >> 8;
    const float* src = Whh + (ct * 16 + (ln & 15)) * 128 + ks * 32 + (ln >> 4) * 8;
    *(bh8*)&whf[idx * 8] = cvt8(*(const fx4*)src, *(const fx4*)(src + 4));
  }
  for (int i = 0; i < 8; ++i) ((int*)hbuf)[tid + i * 512] = 0;

  bh8 wfih[4]; float bias[4];
#pragma unroll
  for (int gate = 0; gate < 4; ++gate) {
    int g = (gate * 8 + w) * 16 + l15;
    bias[gate] = bih[g] + bhh[g];
    const float* src = Wih + g * 32 + l4 * 8;
    wfih[gate] = cvt8(*(const fx4*)src, *(const fx4*)(src + 4));
  }
  bh8 df[4];
  const int rtd = w >> 1, oc = w & 1;
  const int od = oc * 16 + l15;
  const float dbias = db[od];
#pragma unroll
  for (int ks = 0; ks < 4; ++ks) {
    const float* src = dW + od * 128 + ks * 32 + l4 * 8;
    df[ks] = cvt8(*(const fx4*)src, *(const fx4*)(src + 4));
  }

  float cst[4][4];
#pragma unroll
  for (int rt = 0; rt < 4; ++rt)
#pragma unroll
    for (int r = 0; r < 4; ++r) cst[rt][r] = 0.f;

  const int mloc = tid >> 3, a0 = (tid & 7) * 4;
  const long tb0 = (long)bidx * T_ * 8192;
  const long pfoff = (long)(m0 + mloc) * 32 + a0;
  const int ytre = ((mloc >> 4) * 64 + ((a0 >> 3) << 4) + (mloc & 15)) * 8 + (a0 & 7);
  const int kse = w >> 1;
  const int lnhi = (((w & 1) * 2 + (l15 >> 3)) << 4);
  const int e0 = l15 & 7;

  fx4 y4 = *(const fx4*)&yo[tb0 + pfoff];
  {
    sh4 p; p[0] = f2bf(y4[0]); p[1] = f2bf(y4[1]); p[2] = f2bf(y4[2]); p[3] = f2bf(y4[3]);
    *(sh4*)&ytr[ytre] = p;
  }
  y4 = *(const fx4*)&yo[tb0 + 8192 + pfoff];
  __syncthreads();

  for (int t = 0; t < T_; ++t) {
    const long off = tb0 + (long)t * 8192;
    float hn[4][4];
    bh8 Ball[4][4];
#pragma unroll
    for (int gate = 0; gate < 4; ++gate)
#pragma unroll
      for (int ks = 0; ks < 4; ++ks)
        Ball[gate][ks] =
            *(const bh8*)&whf[((((gate * 8 + w) * 4) + ks) * 64 + lane) * 8];
#pragma unroll
    for (int rt = 0; rt < 4; ++rt) {
      bh8 ya = *(const bh8*)&ytr[(rt * 64 + lane) * 8];
      bh8 hA[4];
#pragma unroll
      for (int ks = 0; ks < 4; ++ks)
        hA[ks] = *(const bh8*)&hbuf[((rt * 4 + ks) * 64 + lane) * 8];
      fx4 acc[4];
#pragma unroll
      for (int gate = 0; gate < 4; ++gate) {
        fx4 A = {bias[gate], bias[gate], bias[gate], bias[gate]};
        A = mm16(ya, wfih[gate], A);
#pragma unroll
        for (int ks = 0; ks < 4; ++ks) A = mm16(hA[ks], Ball[gate][ks], A);
        acc[gate] = A;
      }
#pragma unroll
      for (int r = 0; r < 4; ++r) {
        float iv = sigm(acc[0][r]);
        float fv = sigm(acc[1][r]);
        float gv = tanh_f(acc[2][r]);
        float ov = sigm(acc[3][r]);
        float cn = fv * cst[rt][r] + iv * gv;
        cst[rt][r] = cn;
        hn[rt][r] = ov * tanh_f(cn);
      }
    }
    __syncthreads();
#pragma unroll
    for (int rt = 0; rt < 4; ++rt)
#pragma unroll
      for (int r = 0; r < 4; ++r)
        hbuf[((rt * 4 + kse) * 64 + lnhi + l4 * 4 + r) * 8 + e0] = f2bf(hn[rt][r]);
    if (t + 1 < T_) {
      sh4 p; p[0] = f2bf(y4[0]); p[1] = f2bf(y4[1]); p[2] = f2bf(y4[2]); p[3] = f2bf(y4[3]);
      *(sh4*)&ytr[ytre] = p;
    }
    if (t + 2 < T_) y4 = *(const fx4*)&yo[off + 2 * 8192 + pfoff];
    __syncthreads();
    {
      fx4 A = {dbias, dbias, dbias, dbias};
#pragma unroll
      for (int ks = 0; ks < 4; ++ks) {
        bh8 hA2 = *(const bh8*)&hbuf[((rtd * 4 + ks) * 64 + lane) * 8];
        A = mm16(hA2, df[ks], A);
      }
#pragma unroll
      for (int r = 0; r < 4; ++r)
        obuf[(rtd * 16 + l4 * 4 + r) * 36 + oc * 16 + l15] = A[r];
    }
    __syncthreads();
    {
      fx4 o4 = *(const fx4*)&obuf[mloc * 36 + a0];
      *(fx4*)&yo[off + pfoff] = o4;
    }
  }
}

extern "C" void kernel_launch(void* const* d_in, const int* in_sizes, int n_in,
                              void* d_out, int out_size, void* d_ws, size_t ws_size,
                              hipStream_t stream) {
  const float* x   = (const float*)d_in[0];
  const float* aw  = (const float*)d_in[1];
  const float* wih = (const float*)d_in[2];
  const float* whh = (const float*)d_in[3];
  const float* bih = (const float*)d_in[4];
  const float* bhh = (const float*)d_in[5];
  const float* dw  = (const float*)d_in[6];
  const float* db  = (const float*)d_in[7];
  float* out = (float*)d_out;

  const size_t PLANE = (size_t)32 * BT_ * 256;           // elements (bf16)
  const size_t NEED  = 2 * PLANE * sizeof(short);        // u + y = 352MB
  if (d_ws && ws_size >= NEED) {
    short* u = (short*)d_ws;
    short* yv = u + PLANE;
    hipLaunchKernelGGL(atan_tr,    dim3(256), dim3(512), 0, stream, x, u);
    hipLaunchKernelGGL(icfa_gemm2, dim3(256), dim3(512), 0, stream, u, aw, yv);
    hipLaunchKernelGGL(lstm_fused12, dim3(256), dim3(1024), 0, stream,
                       yv, wih, whh, bih, bhh, dw, db, out);
  } else {
    hipLaunchKernelGGL(icfa_mfma, dim3(256), dim3(512), 0, stream, x, aw, out);
    hipLaunchKernelGGL(lstm_fused, dim3(256), dim3(512), 0, stream,
                       wih, whh, bih, bhh, dw, db, out);
  }
}

// Round 13
// 787.003 us; speedup vs baseline: 1.5270x; 1.5270x over previous
//
#include <hip/hip_runtime.h>

#define B_  64
#define T_  168
#define M_  256
#define F_  32
#define H_  128
#define O_  32
#define BT_ (B_*T_)   // 10752

typedef __attribute__((ext_vector_type(8))) short bh8;   // 8 x bf16 bits (4 VGPR)
typedef __attribute__((ext_vector_type(4))) short sh4;   // 4 x bf16 bits (8B)
typedef __attribute__((ext_vector_type(4))) float fx4;

static __device__ __forceinline__ short f2bf(float f) {
  unsigned u = __float_as_uint(f);
  u += 0x7FFFu + ((u >> 16) & 1u);   // round-to-nearest-even
  return (short)(u >> 16);
}
static __device__ __forceinline__ unsigned cvtpk(float lo, float hi) {
  unsigned r;
  asm("v_cvt_pk_bf16_f32 %0, %1, %2" : "=v"(r) : "v"(lo), "v"(hi));
  return r;
}
static __device__ __forceinline__ float ex2_(float x) {
#if __has_builtin(__builtin_amdgcn_exp2f)
  return __builtin_amdgcn_exp2f(x);
#else
  return exp2f(x);
#endif
}
static __device__ __forceinline__ float rcp_(float x) {
#if __has_builtin(__builtin_amdgcn_rcpf)
  return __builtin_amdgcn_rcpf(x);
#else
  return 1.0f / x;
#endif
}
static __device__ __forceinline__ float sigm(float x) {
  return 1.0f / (1.0f + __expf(-x));
}
static __device__ __forceinline__ float tanh_f(float x) {
  return 1.0f - 2.0f / (1.0f + __expf(2.0f * x));
}
static __device__ __forceinline__ fx4 mm16(bh8 a, bh8 b, fx4 c) {
  return __builtin_amdgcn_mfma_f32_16x16x32_bf16(a, b, c, 0, 0, 0);
}
static __device__ __forceinline__ bh8 cvt8(fx4 p0, fx4 p1) {
  bh8 s;
  s[0] = f2bf(p0[0]); s[1] = f2bf(p0[1]); s[2] = f2bf(p0[2]); s[3] = f2bf(p0[3]);
  s[4] = f2bf(p1[0]); s[5] = f2bf(p1[1]); s[6] = f2bf(p1[2]); s[7] = f2bf(p1[3]);
  return s;
}

// ================== NEW PATH (needs 352MB workspace) ==================

// ---- K1: x [bt][n][a] f32 -> u [a][bt][n] bf16, atan applied once.
__global__ __launch_bounds__(512) void atan_tr(const float* __restrict__ x,
                                               short* __restrict__ ut) {
  __shared__ __align__(16) short tl[8 * 32 * 68];   // 34.8KB -> 4 blocks/CU
  const int tid = threadIdx.x;
  const float c2p = 0.63661977236758134f;  // 2/pi
  for (int it = 0; it < 21; ++it) {
    const int id = blockIdx.x + it * 256;       // 5376 tiles total
    const int bt0 = (id >> 2) * 8, n0 = (id & 3) * 64;
    if (it) __syncthreads();
#pragma unroll
    for (int i = 0; i < 8; ++i) {
      int idx = tid + i * 512;
      int aq = idx & 7, nl = (idx >> 3) & 63, btl = idx >> 9;
      const float* src = x + (long)(bt0 + btl) * 8192 + (n0 + nl) * 32 + aq * 4;
      fx4 v = *(const fx4*)src;
      int base = (btl * 32 + aq * 4) * 68 + nl;
#pragma unroll
      for (int k = 0; k < 4; ++k)
        tl[base + k * 68] = f2bf(atanf(v[k]) * c2p);
    }
    __syncthreads();
#pragma unroll
    for (int p = 0; p < 8; ++p) {
      int r = p * 32 + (tid >> 4);              // (a, btl) row
      int a = r >> 3, btl = r & 7, nq = tid & 15;
      sh4 v = *(const sh4*)&tl[(btl * 32 + a) * 68 + nq * 4];
      *(sh4*)&ut[((long)a * BT_ + bt0 + btl) * 256 + n0 + nq * 4] = v;
    }
  }
}

// ---- K2 v2: y[a][bt][m] (bf16) = W[a] (m x n) * u[a] (n x bt).
// BOTH W-halves' A-frags hoisted to registers -> u streamed once.
__global__ __launch_bounds__(512) void icfa_gemm2(const short* __restrict__ ut,
                                                  const float* __restrict__ aw,
                                                  short* __restrict__ y) {
  __shared__ __align__(16) short waf[8 * 8 * 64 * 8];   // 64KB A-frag staging
  __shared__ __align__(16) short ubf[64 * 256];         // 32KB swizzled B tile
  const int tid = threadIdx.x;
  const int lane = tid & 63, w = tid >> 6, l15 = lane & 15, l4 = lane >> 4;
  const int a = blockIdx.x >> 3, s = blockIdx.x & 7;
  const long ua = (long)a * BT_;

  bh8 Af[2][8];
#pragma unroll
  for (int mh = 0; mh < 2; ++mh) {
    if (mh) __syncthreads();              // Af[0] hoist reads done before repack
    for (int i = 0; i < 8; ++i) {
      int idx = tid + i * 512;
      int ln = idx & 63, ks = (idx >> 6) & 7, mt = idx >> 9;
      const float* src = aw + a * 65536 + (mh * 128 + mt * 16 + (ln & 15)) * 256
                         + ks * 32 + (ln >> 4) * 8;
      *(bh8*)&waf[idx * 8] = cvt8(*(const fx4*)src, *(const fx4*)(src + 4));
    }
    __syncthreads();
#pragma unroll
    for (int ks = 0; ks < 8; ++ks)
      Af[mh][ks] = *(const bh8*)&waf[((w * 8 + ks) * 64 + lane) * 8];
  }

  for (int tile = 0; tile < 21; ++tile) {
    const int bt0 = s * 1344 + tile * 64;
    __syncthreads();   // prev tile's ubf reads done
#pragma unroll
    for (int i = 0; i < 4; ++i) {
      int idx = tid + i * 512;               // 16B units
      int row = idx >> 5, slot = idx & 31;
      bh8 v = *(const bh8*)&ut[(ua + bt0 + row) * 256 + slot * 8];
      int sb = (row * 512 + slot * 16) ^ ((row & 7) << 4);
      *(bh8*)&((char*)ubf)[sb] = v;
    }
    __syncthreads();
#pragma unroll
    for (int ct = 0; ct < 4; ++ct) {
      fx4 acc0 = {0.f, 0.f, 0.f, 0.f};
      fx4 acc1 = {0.f, 0.f, 0.f, 0.f};
      const int btr = ct * 16 + l15;
#pragma unroll
      for (int ks = 0; ks < 8; ++ks) {
        int byo = (btr * 512 + ks * 64 + l4 * 16) ^ ((btr & 7) << 4);
        bh8 Bf = *(const bh8*)&((char*)ubf)[byo];
        acc0 = mm16(Af[0][ks], Bf, acc0);
        acc1 = mm16(Af[1][ks], Bf, acc1);
      }
      sh4 o0, o1;
      o0[0] = f2bf(acc0[0]); o0[1] = f2bf(acc0[1]);
      o0[2] = f2bf(acc0[2]); o0[3] = f2bf(acc0[3]);
      o1[0] = f2bf(acc1[0]); o1[1] = f2bf(acc1[1]);
      o1[2] = f2bf(acc1[2]); o1[3] = f2bf(acc1[3]);
      long yb = (ua + bt0 + btr) * 256 + w * 16 + l4 * 4;
      *(sh4*)&y[yb]       = o0;
      *(sh4*)&y[yb + 128] = o1;
    }
  }
}

// ---- Stage 2 v11 (best known): 16 waves, whf LDS, 272B hx, swapped-D,
// rcp-merged pointwise, swizzled ytr.
__global__ __launch_bounds__(1024) void lstm_fused11(
    const short* __restrict__ y,
    const float* __restrict__ Wih, const float* __restrict__ Whh,
    const float* __restrict__ bih, const float* __restrict__ bhh,
    const float* __restrict__ dW,  const float* __restrict__ db,
    float* __restrict__ out) {
  __shared__ __align__(16) short whf[65536];  // 128KB Whh A-frags (wg,gate,ks,lane)
  __shared__ __align__(16) short hx[8704];    // 17.4KB h [64][128+8] stride 272B
  __shared__ __align__(16) short ytr[2048];   // 4KB y frags (swizzled half layout)
  const int tid = threadIdx.x;
  const int lane = tid & 63, w = tid >> 6, l15 = lane & 15, l4 = lane >> 4;
  const int wg = w & 7, hw = w >> 3;
  const int bidx = blockIdx.x >> 2, m0 = (blockIdx.x & 3) * 64;
  const float L2E = 1.4426950408889634f;

  // ---- pack Whh A-frags wave-contiguous (immediate offsets per wave)
  for (int i = 0; i < 8; ++i) {
    int idx = tid + i * 1024;
    int ln = idx & 63, ks = (idx >> 6) & 3, gate = (idx >> 8) & 3, wgp = idx >> 10;
    const float* src = Whh + ((gate * 8 + wgp) * 16 + (ln & 15)) * 128
                       + ks * 32 + (ln >> 4) * 8;
    *(bh8*)&whf[idx * 8] = cvt8(*(const fx4*)src, *(const fx4*)(src + 4));
  }
  // ---- h0 = 0 (8704 shorts = 4352 ints)
  for (int i = 0; i < 5; ++i) {
    int j = tid + i * 1024;
    if (j < 4352) ((int*)hx)[j] = 0;
  }

  // ---- Wih A-frags + per-row folded biases (D row g = grow + l4*4 + r)
  bh8 wfih[4]; float nb[4][4];
#pragma unroll
  for (int gate = 0; gate < 4; ++gate) {
    int grow = (gate * 8 + wg) * 16;
    const float* src = Wih + (grow + l15) * 32 + l4 * 8;
    wfih[gate] = cvt8(*(const fx4*)src, *(const fx4*)(src + 4));
#pragma unroll
    for (int r = 0; r < 4; ++r) {
      int g = grow + l4 * 4 + r;
      float b = bih[g] + bhh[g];
      nb[gate][r] = (gate == 2) ? (2.0f * L2E * b) : (-L2E * b);
    }
  }
  // ---- dense A-frags: waves wg<4: oc = wg&1, m-tile mt_d = 2hw + (wg>>1)
  bh8 df[4]; float dbv[4];
  const int oc = wg & 1, mt_d = hw * 2 + ((wg >> 1) & 1);
#pragma unroll
  for (int ks = 0; ks < 4; ++ks) {
    const float* src = dW + (oc * 16 + l15) * 128 + ks * 32 + l4 * 8;
    df[ks] = cvt8(*(const fx4*)src, *(const fx4*)(src + 4));
  }
#pragma unroll
  for (int r = 0; r < 4; ++r) dbv[r] = db[oc * 16 + l4 * 4 + r];

  float cst[2][4];
#pragma unroll
  for (int mt = 0; mt < 2; ++mt)
#pragma unroll
    for (int r = 0; r < 4; ++r) cst[mt][r] = 0.f;

  // ---- address bases (hx stride 272B; all loop offsets immediates)
  char* hxc = (char*)hx;
  const int hrb = (hw * 32 + l15) * 272 + l4 * 16;        // gates B read, tile 2hw
  const int hdb = (mt_d * 16 + l15) * 272 + l4 * 16;      // dense B read
  const int hwb = (hw * 32 + l15) * 272 + wg * 32 + l4 * 8;  // h b64 write
  // y-read mapping: thread -> (attr ar, m-pair mq2)
  const int ar = tid >> 5, mq2 = tid & 31;
  const long yrow = (long)ar * BT_ + (long)bidx * T_;
  // ytr WRITE indices (swizzled half layout); R0 even
  const int ml0 = mq2 * 2;
  const int R0 = (ml0 >> 4) * 64 + ((ar >> 3) << 4) + (ml0 & 15);
  const int eA = ar & 7, hA = eA >> 2, ehA = eA & 3;
  const int rl0 = (R0 & 15) ^ ((R0 >> 6) & 3);
  const int yw0 = hA * 1024 + rl0 * 4 + ((R0 >> 4) & 15) * 64 + ehA;
  const int yw1 = yw0 + 4 - 8 * (rl0 & 1);     // row R0+1 (flip bit0 of rl)
  // ytr READ bases (per wave: tiles 2hw, 2hw+1), b64 each half
  const int mtA = 2 * hw, mtB = 2 * hw + 1;
  const int ybA0 = ((lane & 15) ^ (mtA & 3)) * 4 + (mtA * 4 + l4) * 64;        // h=0
  const int ybB0 = ((lane & 15) ^ (mtB & 3)) * 4 + (mtB * 4 + l4) * 64;        // h=0
  // dense out base
  const long obB = (long)bidx * T_ * 8192
                 + (long)(m0 + mt_d * 16 + l15) * 32 + oc * 16 + l4 * 4;

  // ---- prologue: ytr(0), prefetch y(1)
  int ys = *(const int*)&y[(yrow + 0) * 256 + m0 + mq2 * 2];
  ytr[yw0] = (short)(ys & 0xffff);
  ytr[yw1] = (short)(((unsigned)ys) >> 16);
  ys = *(const int*)&y[(yrow + 1) * 256 + m0 + mq2 * 2];
  __syncthreads();

  for (int t = 0; t < T_; ++t) {
    // ---- phase A: gates GEMM D[g][m] + dense(t-1) + pointwise
    int ysn = 0;
    if (t + 2 < T_) ysn = *(const int*)&y[(yrow + t + 2) * 256 + m0 + mq2 * 2];
    fx4 acc[4][2];
    {
      sh4 a0 = *(const sh4*)&ytr[ybA0];
      sh4 a1 = *(const sh4*)&ytr[ybA0 + 1024];
      sh4 b0 = *(const sh4*)&ytr[ybB0];
      sh4 b1 = *(const sh4*)&ytr[ybB0 + 1024];
      bh8 yB0 = __builtin_shufflevector(a0, a1, 0, 1, 2, 3, 4, 5, 6, 7);
      bh8 yB1 = __builtin_shufflevector(b0, b1, 0, 1, 2, 3, 4, 5, 6, 7);
      fx4 Z = {0.f, 0.f, 0.f, 0.f};
#pragma unroll
      for (int g = 0; g < 4; ++g) {
        acc[g][0] = mm16(wfih[g], yB0, Z);
        acc[g][1] = mm16(wfih[g], yB1, Z);
      }
    }
#pragma unroll
    for (int ks = 0; ks < 4; ++ks) {
      bh8 hB0 = *(const bh8*)(hxc + hrb + ks * 64);
      bh8 hB1 = *(const bh8*)(hxc + hrb + 4352 + ks * 64);
#pragma unroll
      for (int g = 0; g < 4; ++g) {
        bh8 Af = *(const bh8*)((const char*)whf
                               + ((wg * 16 + g * 4 + ks) * 64 + lane) * 16);
        acc[g][0] = mm16(Af, hB0, acc[g][0]);
        acc[g][1] = mm16(Af, hB1, acc[g][1]);
      }
    }
    // dense head for t-1 (reads hx = h_{t-1}) -> contiguous fx4 global store
    if (wg < 4 && t > 0) {
      fx4 A = {dbv[0], dbv[1], dbv[2], dbv[3]};
#pragma unroll
      for (int ks = 0; ks < 4; ++ks) {
        bh8 hd = *(const bh8*)(hxc + hdb + ks * 64);
        A = mm16(df[ks], hd, A);
      }
      *(fx4*)&out[obB + (long)(t - 1) * 8192] = A;
    }
    // pointwise: rcp-merged, 5 exp2 + 2 rcp per cell
    float hn[2][4];
#pragma unroll
    for (int mt = 0; mt < 2; ++mt)
#pragma unroll
      for (int r = 0; r < 4; ++r) {
        float eI = ex2_(fmaf(acc[0][mt][r], -L2E, nb[0][r]));      // e^{-i'}
        float eF = ex2_(fmaf(acc[1][mt][r], -L2E, nb[1][r]));      // e^{-f'}
        float eG = ex2_(fmaf(acc[2][mt][r], 2.f * L2E, nb[2][r])); // e^{2g'}
        float eO = ex2_(fmaf(acc[3][mt][r], -L2E, nb[3][r]));      // e^{-o'}
        float pi = 1.f + eI, pf = 1.f + eF, pg = 1.f + eG;
        float pig = pi * pg;
        float num = fmaf(cst[mt][r], pig, (eG - 1.f) * pf);
        float cn = num * rcp_(pf * pig);
        cst[mt][r] = cn;
        float eC = ex2_(cn * (2.f * L2E));                         // e^{2cn}
        hn[mt][r] = (eC - 1.f) * rcp_((1.f + eO) * (1.f + eC));
      }
    __syncthreads();                       // B_A: all hx/ytr reads done
    // ---- phase B: write hx <- h_t (one b64 per m-tile), ytr <- y(t+1)
#pragma unroll
    for (int mt = 0; mt < 2; ++mt) {
      unsigned p01 = cvtpk(hn[mt][0], hn[mt][1]);
      unsigned p23 = cvtpk(hn[mt][2], hn[mt][3]);
      *(unsigned long long*)(hxc + hwb + mt * 4352) =
          (((unsigned long long)p23) << 32) | p01;
    }
    if (t + 1 < T_) {
      ytr[yw0] = (short)(ys & 0xffff);
      ytr[yw1] = (short)(((unsigned)ys) >> 16);
    }
    ys = ysn;
    __syncthreads();                       // B_B: writes visible
  }
  // ---- epilogue: dense(T-1) from hx = h_{T-1}
  if (wg < 4) {
    fx4 A = {dbv[0], dbv[1], dbv[2], dbv[3]};
#pragma unroll
    for (int ks = 0; ks < 4; ++ks) {
      bh8 hd = *(const bh8*)(hxc + hdb + ks * 64);
      A = mm16(df[ks], hd, A);
    }
    *(fx4*)&out[obB + (long)(T_ - 1) * 8192] = A;
  }
}

// ================== OLD PATH (fallback if workspace too small) ==================

__global__ __launch_bounds__(512) void icfa_mfma(const float* __restrict__ x,
                                                 const float* __restrict__ aw,
                                                 float* __restrict__ y) {
  __shared__ short waf[8 * 8 * 64 * 8];
  __shared__ short ubf[64 * 264];
  const int tid = threadIdx.x;
  const int lane = tid & 63, w = tid >> 6, l15 = lane & 15, l4 = lane >> 4;
  const int a = blockIdx.x >> 3, s = blockIdx.x & 7;
  const float c2p = 0.63661977236758134f;

  for (int mh = 0; mh < 2; ++mh) {
    __syncthreads();
    for (int i = 0; i < 8; ++i) {
      int idx = tid + i * 512;
      int ln = idx & 63, ks = (idx >> 6) & 7, mt = idx >> 9;
      const float* src = aw + a * 65536 + (mh * 128 + mt * 16 + (ln & 15)) * 256
                         + ks * 32 + (ln >> 4) * 8;
      *(bh8*)&waf[idx * 8] = cvt8(*(const fx4*)src, *(const fx4*)(src + 4));
    }
    __syncthreads();
    bh8 Af[8];
#pragma unroll
    for (int ks = 0; ks < 8; ++ks)
      Af[ks] = *(const bh8*)&waf[((w * 8 + ks) * 64 + lane) * 8];

    for (int tile = 0; tile < 21; ++tile) {
      const int bt0 = s * 1344 + tile * 64;
      __syncthreads();
#pragma unroll 4
      for (int i = 0; i < 32; ++i) {
        int idx = tid + i * 512;
        int n = idx & 255, btc = idx >> 8;
        float v = x[(long)(bt0 + btc) * 8192 + n * 32 + a];
        ubf[btc * 264 + n] = f2bf(atanf(v) * c2p);
      }
      __syncthreads();
#pragma unroll
      for (int ct = 0; ct < 4; ++ct) {
        fx4 acc = {0.f, 0.f, 0.f, 0.f};
#pragma unroll
        for (int ks = 0; ks < 8; ++ks) {
          bh8 Bf = *(const bh8*)&ubf[(ct * 16 + l15) * 264 + ks * 32 + l4 * 8];
          acc = mm16(Af[ks], Bf, acc);
        }
        long ybase = (long)(bt0 + ct * 16 + l15) * 8192
                     + (mh * 128 + w * 16 + l4 * 4) * 32 + a;
#pragma unroll
        for (int r = 0; r < 4; ++r) y[ybase + (long)r * 32] = acc[r];
      }
    }
  }
}

__global__ __launch_bounds__(512) void lstm_fused(
    const float* __restrict__ Wih, const float* __restrict__ Whh,
    const float* __restrict__ bih, const float* __restrict__ bhh,
    const float* __restrict__ dW,  const float* __restrict__ db,
    float* __restrict__ yo) {
  __shared__ short whf[32 * 4 * 64 * 8];
  __shared__ short hbuf[4 * 4 * 64 * 8];
  __shared__ short ytr[4 * 64 * 8];
  __shared__ float obuf[64 * 36];
  const int tid = threadIdx.x;
  const int lane = tid & 63, w = tid >> 6, l15 = lane & 15, l4 = lane >> 4;
  const int bidx = blockIdx.x >> 2, m0 = (blockIdx.x & 3) * 64;

  for (int i = 0; i < 16; ++i) {
    int idx = tid + i * 512;
    int ln = idx & 63, ks = (idx >> 6) & 3, ct = idx >> 8;
    const float* src = Whh + (ct * 16 + (ln & 15)) * 128 + ks * 32 + (ln >> 4) * 8;
    *(bh8*)&whf[idx * 8] = cvt8(*(const fx4*)src, *(const fx4*)(src + 4));
  }
  for (int i = 0; i < 8; ++i) ((int*)hbuf)[tid + i * 512] = 0;

  bh8 wfih[4]; float bias[4];
#pragma unroll
  for (int gate = 0; gate < 4; ++gate) {
    int g = (gate * 8 + w) * 16 + l15;
    bias[gate] = bih[g] + bhh[g];
    const float* src = Wih + g * 32 + l4 * 8;
    wfih[gate] = cvt8(*(const fx4*)src, *(const fx4*)(src + 4));
  }
  bh8 df[4];
  const int rtd = w >> 1, oc = w & 1;
  const int od = oc * 16 + l15;
  const float dbias = db[od];
#pragma unroll
  for (int ks = 0; ks < 4; ++ks) {
    const float* src = dW + od * 128 + ks * 32 + l4 * 8;
    df[ks] = cvt8(*(const fx4*)src, *(const fx4*)(src + 4));
  }

  float cst[4][4];
#pragma unroll
  for (int rt = 0; rt < 4; ++rt)
#pragma unroll
    for (int r = 0; r < 4; ++r) cst[rt][r] = 0.f;

  const int mloc = tid >> 3, a0 = (tid & 7) * 4;
  const long tb0 = (long)bidx * T_ * 8192;
  const long pfoff = (long)(m0 + mloc) * 32 + a0;
  const int ytre = ((mloc >> 4) * 64 + ((a0 >> 3) << 4) + (mloc & 15)) * 8 + (a0 & 7);
  const int kse = w >> 1;
  const int lnhi = (((w & 1) * 2 + (l15 >> 3)) << 4);
  const int e0 = l15 & 7;

  fx4 y4 = *(const fx4*)&yo[tb0 + pfoff];
  {
    sh4 p; p[0] = f2bf(y4[0]); p[1] = f2bf(y4[1]); p[2] = f2bf(y4[2]); p[3] = f2bf(y4[3]);
    *(sh4*)&ytr[ytre] = p;
  }
  y4 = *(const fx4*)&yo[tb0 + 8192 + pfoff];
  __syncthreads();

  for (int t = 0; t < T_; ++t) {
    const long off = tb0 + (long)t * 8192;
    float hn[4][4];
    bh8 Ball[4][4];
#pragma unroll
    for (int gate = 0; gate < 4; ++gate)
#pragma unroll
      for (int ks = 0; ks < 4; ++ks)
        Ball[gate][ks] =
            *(const bh8*)&whf[((((gate * 8 + w) * 4) + ks) * 64 + lane) * 8];
#pragma unroll
    for (int rt = 0; rt < 4; ++rt) {
      bh8 ya = *(const bh8*)&ytr[(rt * 64 + lane) * 8];
      bh8 hA[4];
#pragma unroll
      for (int ks = 0; ks < 4; ++ks)
        hA[ks] = *(const bh8*)&hbuf[((rt * 4 + ks) * 64 + lane) * 8];
      fx4 acc[4];
#pragma unroll
      for (int gate = 0; gate < 4; ++gate) {
        fx4 A = {bias[gate], bias[gate], bias[gate], bias[gate]};
        A = mm16(ya, wfih[gate], A);
#pragma unroll
        for (int ks = 0; ks < 4; ++ks) A = mm16(hA[ks], Ball[gate][ks], A);
        acc[gate] = A;
      }
#pragma unroll
      for (int r = 0; r < 4; ++r) {
        float iv = sigm(acc[0][r]);
        float fv = sigm(acc[1][r]);
        float gv = tanh_f(acc[2][r]);
        float ov = sigm(acc[3][r]);
        float cn = fv * cst[rt][r] + iv * gv;
        cst[rt][r] = cn;
        hn[rt][r] = ov * tanh_f(cn);
      }
    }
    __syncthreads();
#pragma unroll
    for (int rt = 0; rt < 4; ++rt)
#pragma unroll
      for (int r = 0; r < 4; ++r)
        hbuf[((rt * 4 + kse) * 64 + lnhi + l4 * 4 + r) * 8 + e0] = f2bf(hn[rt][r]);
    if (t + 1 < T_) {
      sh4 p; p[0] = f2bf(y4[0]); p[1] = f2bf(y4[1]); p[2] = f2bf(y4[2]); p[3] = f2bf(y4[3]);
      *(sh4*)&ytr[ytre] = p;
    }
    if (t + 2 < T_) y4 = *(const fx4*)&yo[off + 2 * 8192 + pfoff];
    __syncthreads();
    {
      fx4 A = {dbias, dbias, dbias, dbias};
#pragma unroll
      for (int ks = 0; ks < 4; ++ks) {
        bh8 hA2 = *(const bh8*)&hbuf[((rtd * 4 + ks) * 64 + lane) * 8];
        A = mm16(hA2, df[ks], A);
      }
#pragma unroll
      for (int r = 0; r < 4; ++r)
        obuf[(rtd * 16 + l4 * 4 + r) * 36 + oc * 16 + l15] = A[r];
    }
    __syncthreads();
    {
      fx4 o4 = *(const fx4*)&obuf[mloc * 36 + a0];
      *(fx4*)&yo[off + pfoff] = o4;
    }
  }
}

extern "C" void kernel_launch(void* const* d_in, const int* in_sizes, int n_in,
                              void* d_out, int out_size, void* d_ws, size_t ws_size,
                              hipStream_t stream) {
  const float* x   = (const float*)d_in[0];
  const float* aw  = (const float*)d_in[1];
  const float* wih = (const float*)d_in[2];
  const float* whh = (const float*)d_in[3];
  const float* bih = (const float*)d_in[4];
  const float* bhh = (const float*)d_in[5];
  const float* dw  = (const float*)d_in[6];
  const float* db  = (const float*)d_in[7];
  float* out = (float*)d_out;

  const size_t PLANE = (size_t)32 * BT_ * 256;           // elements (bf16)
  const size_t NEED  = 2 * PLANE * sizeof(short);        // u + y = 352MB
  if (d_ws && ws_size >= NEED) {
    short* u = (short*)d_ws;
    short* yv = u + PLANE;
    hipLaunchKernelGGL(atan_tr,    dim3(256), dim3(512), 0, stream, x, u);
    hipLaunchKernelGGL(icfa_gemm2, dim3(256), dim3(512), 0, stream, u, aw, yv);
    hipLaunchKernelGGL(lstm_fused11, dim3(256), dim3(1024), 0, stream,
                       yv, wih, whh, bih, bhh, dw, db, out);
  } else {
    hipLaunchKernelGGL(icfa_mfma, dim3(256), dim3(512), 0, stream, x, aw, out);
    hipLaunchKernelGGL(lstm_fused, dim3(256), dim3(512), 0, stream,
                       wih, whh, bih, bhh, dw, db, out);
  }
}